// Round 5
// baseline (1144.019 us; speedup 1.0000x reference)
//
#include <hip/hip_runtime.h>

#define B_ 4
#define C_ 256
#define N_ 4096

typedef float f32x4 __attribute__((ext_vector_type(4)));
typedef float f32x16 __attribute__((ext_vector_type(16)));
typedef _Float16 f16x8 __attribute__((ext_vector_type(8)));
typedef _Float16 f16x4 __attribute__((ext_vector_type(4)));
typedef _Float16 f16x2 __attribute__((ext_vector_type(2)));
typedef unsigned u32x4 __attribute__((ext_vector_type(4)));

__device__ __forceinline__ unsigned pk2(float a, float b) {
  f16x2 t = {(_Float16)a, (_Float16)b};
  return __builtin_bit_cast(unsigned, t);
}
__device__ __forceinline__ void gll16(const void* g, void* l) {
  __builtin_amdgcn_global_load_lds(
      (const __attribute__((address_space(1))) unsigned*)g,
      (__attribute__((address_space(3))) unsigned*)l, 16, 0, 0);
}

// ---------------- kernel 0: W fp32 -> fp16 ----------------
__global__ void wconv_kernel(const float* __restrict__ Wq, const float* __restrict__ Wk,
                             const float* __restrict__ Wv,
                             _Float16* __restrict__ wqf, _Float16* __restrict__ wkf,
                             _Float16* __restrict__ wvf) {
  int i = blockIdx.x * 256 + threadIdx.x;
  wqf[i] = (_Float16)Wq[i];
  wkf[i] = (_Float16)Wk[i];
  wvf[i] = (_Float16)Wv[i];
}

// ---------------- kernel 1: QKV projection, full 256-o per block ----------------
// grid (64 n-tiles, 4 b), 256 thr. LDS-bounce epilogues for coalesced stores.
__global__ __launch_bounds__(256) void proj_kernel(
    const float* __restrict__ x,
    const _Float16* __restrict__ wqf, const _Float16* __restrict__ wkf,
    const _Float16* __restrict__ wvf,
    const float* __restrict__ bq, const float* __restrict__ bk,
    const float* __restrict__ bv,
    _Float16* __restrict__ Qf, _Float16* __restrict__ Kf, _Float16* __restrict__ Vf) {
  __shared__ __align__(16) _Float16 xT[64 * 264];   // [n][c], pitch 264
  __shared__ __align__(16) char oBuf[36864];        // Q/K: [64 n][264 o] f16; V: [256 o][72 n] f16
  const int t = threadIdx.x;
  const int n0 = blockIdx.x * 64, b = blockIdx.y;
  const float* xb = x + (size_t)b * C_ * N_ + n0;

  // stage x tile transposed to f16: 4c x 4n micro-transposes
  #pragma unroll
  for (int it = 0; it < 4; ++it) {
    int c0 = ((t >> 4) + it * 16) * 4;
    int n4 = (t & 15) * 4;
    f32x4 r0 = *(const f32x4*)(xb + (size_t)(c0 + 0) * N_ + n4);
    f32x4 r1 = *(const f32x4*)(xb + (size_t)(c0 + 1) * N_ + n4);
    f32x4 r2 = *(const f32x4*)(xb + (size_t)(c0 + 2) * N_ + n4);
    f32x4 r3 = *(const f32x4*)(xb + (size_t)(c0 + 3) * N_ + n4);
    #pragma unroll
    for (int nn = 0; nn < 4; ++nn) {
      f16x4 v = {(_Float16)r0[nn], (_Float16)r1[nn], (_Float16)r2[nn], (_Float16)r3[nn]};
      *(f16x4*)(xT + (n4 + nn) * 264 + c0) = v;
    }
  }
  __syncthreads();

  const int wv = t >> 6, lane = t & 63, l15 = lane & 15, lg = lane >> 4;
  _Float16* oB = (_Float16*)oBuf;

  // ---- Q and K paths: D[n][o], wave owns 16 n-rows, loops all 16 o-tiles ----
  #pragma unroll
  for (int path = 0; path < 2; ++path) {
    const _Float16* wp = path ? wkf : wqf;
    const float* bp = path ? bk : bq;
    _Float16* op = path ? Kf : Qf;
    f32x4 acc[16];
    #pragma unroll
    for (int os = 0; os < 16; ++os)
      #pragma unroll
      for (int e = 0; e < 4; ++e) acc[os][e] = 0.f;
    #pragma unroll
    for (int cs = 0; cs < 8; ++cs) {
      int c0 = cs * 32 + lg * 8;
      f16x8 a = *(const f16x8*)(xT + (wv * 16 + l15) * 264 + c0);
      #pragma unroll
      for (int os = 0; os < 16; ++os) {
        f16x8 bb = *(const f16x8*)(wp + (size_t)(os * 16 + l15) * 256 + c0);
        acc[os] = __builtin_amdgcn_mfma_f32_16x16x32_f16(a, bb, acc[os], 0, 0, 0);
      }
    }
    if (path == 1) __syncthreads();   // Q coop-store reads of oB done
    #pragma unroll
    for (int os = 0; os < 16; ++os) {
      int o = os * 16 + l15;
      float bbv = bp[o];
      #pragma unroll
      for (int r = 0; r < 4; ++r)
        oB[(wv * 16 + lg * 4 + r) * 264 + o] = (_Float16)(acc[os][r] + bbv);
    }
    __syncthreads();
    {
      int row = t >> 2, q4 = t & 3;
      const char* src = (const char*)oB + row * 528 + q4 * 16;
      char* dst = (char*)op + ((size_t)(b * N_ + n0 + row)) * 512 + q4 * 16;
      #pragma unroll
      for (int u = 0; u < 8; ++u)
        *(f16x8*)(dst + u * 64) = *(const f16x8*)(src + u * 64);
    }
  }

  // ---- V path: D[o][n], wave owns 64 o-rows x all 4 n-tiles ----
  {
    f32x4 acc[4][4];
    #pragma unroll
    for (int oi = 0; oi < 4; ++oi)
      #pragma unroll
      for (int nt = 0; nt < 4; ++nt)
        #pragma unroll
        for (int e = 0; e < 4; ++e) acc[oi][nt][e] = 0.f;
    #pragma unroll
    for (int cs = 0; cs < 8; ++cs) {
      int c0 = cs * 32 + lg * 8;
      f16x8 a[4];
      #pragma unroll
      for (int oi = 0; oi < 4; ++oi)
        a[oi] = *(const f16x8*)(wvf + (size_t)(wv * 64 + oi * 16 + l15) * 256 + c0);
      #pragma unroll
      for (int nt = 0; nt < 4; ++nt) {
        f16x8 bb = *(const f16x8*)(xT + (nt * 16 + l15) * 264 + c0);
        #pragma unroll
        for (int oi = 0; oi < 4; ++oi)
          acc[oi][nt] = __builtin_amdgcn_mfma_f32_16x16x32_f16(a[oi], bb, acc[oi][nt], 0, 0, 0);
      }
    }
    __syncthreads();   // K coop-store reads of oB done
    #pragma unroll
    for (int oi = 0; oi < 4; ++oi)
      #pragma unroll
      for (int r = 0; r < 4; ++r) {
        int o = wv * 64 + oi * 16 + lg * 4 + r;
        float bbv = bv[o];
        #pragma unroll
        for (int nt = 0; nt < 4; ++nt)
          oB[o * 72 + nt * 16 + l15] = (_Float16)(acc[oi][nt][r] + bbv);
      }
    __syncthreads();
    {
      const char* src = oBuf + t * 144;
      char* dst = (char*)Vf + ((size_t)(b * C_ + t)) * 8192 + n0 * 2;
      #pragma unroll
      for (int u = 0; u < 8; ++u)
        *(f16x8*)(dst + u * 16) = *(const f16x8*)(src + u * 16);
    }
  }
}

// ---------------- kernel 2: flash attention partials ----------------
// grid (16 i-macro, 8 jq, 4 b) = 512 blocks -> 2 blocks/CU. 512 thr = 8 waves,
// wave owns 32 i-rows; block walks 16 tiles of 32 j over its 512-j slice.
// 2-phase double-buffered global_load_lds staging, one barrier/iter, setprio
// around MFMA clusters. Outputs unnormalized O (f16) + m/l planes (f32).
__global__ __launch_bounds__(512, 4) void attn_kernel(
    const _Float16* __restrict__ Qf, const _Float16* __restrict__ Kf,
    const _Float16* __restrict__ Vf,
    _Float16* __restrict__ pO, float* __restrict__ pml) {
  __shared__ __align__(16) char smem[65536];  // K dbuf 2x16KB + V dbuf 2x16KB

  const int t = threadIdx.x;
  const int w = t >> 6, lane = t & 63;
  const int l31 = lane & 31, hi = lane >> 5;
  const int i0 = blockIdx.x * 256, jq = blockIdx.y, b = blockIdx.z;

  char* kb0 = smem;
  char* kb1 = smem + 16384;
  char* vb0 = smem + 32768;
  char* vb1 = smem + 49152;

  // ---- Q prologue: lane column = own query row ----
  const int irow = i0 + w * 32 + l31;
  const _Float16* qb = Qf + ((size_t)(b * N_ + irow)) * C_;
  f16x8 qf[16];
  #pragma unroll
  for (int ks = 0; ks < 16; ++ks) qf[ks] = *(const f16x8*)(qb + ks * 16 + hi * 8);

  f32x16 oacc[8];
  #pragma unroll
  for (int ct = 0; ct < 8; ++ct)
    #pragma unroll
    for (int e = 0; e < 16; ++e) oacc[ct][e] = 0.f;
  float m = -1e30f, lsum = 0.f;

  const char* Kg = (const char*)(Kf + (size_t)b * N_ * C_);
  const char* Vg = (const char*)(Vf + (size_t)b * C_ * N_);
  const int jb0 = jq * 512;

  const int kxread = l31 << 9;
  const int vq = (l31 >> 3) & 3;
  const int vr0 = l31 * 64 + ((hi ^ vq) << 4);
  const int vr1 = l31 * 64 + (((2 | hi) ^ vq) << 4);

  // K LDS [32 j][32 slots of 16B], slot s holds global c-slot (s^j)&31.
  // V LDS [256 c][4 slots of 16B], slot s holds global j-slot s^((c>>3)&3).
#define STAGE(kd_, vd_, jtn) do {                                                \
    int jb_ = jb0 + (jtn) * 32;                                                  \
    const char* kg_ = Kg + ((size_t)jb_ << 9);                                   \
    _Pragma("unroll")                                                            \
    for (int u = 0; u < 2; ++u) {                                                \
      int jl_ = w * 4 + u * 2 + (lane >> 5);                                     \
      gll16(kg_ + (jl_ << 9) + ((((lane & 31) ^ jl_) & 31) << 4),                \
            (kd_) + (w * 4 + u * 2) * 512);                                      \
    }                                                                            \
    const char* vg_ = Vg + ((size_t)jb_ << 1);                                   \
    _Pragma("unroll")                                                            \
    for (int u = 0; u < 2; ++u) {                                                \
      int c_ = w * 32 + u * 16 + (lane >> 2);                                    \
      gll16(vg_ + ((size_t)c_ << 13) + (((lane & 3) ^ ((c_ >> 3) & 3)) << 4),    \
            (vd_) + (w * 32 + u * 16) * 64);                                     \
    }                                                                            \
  } while (0)

  STAGE(kb0, vb0, 0);
  __syncthreads();

  for (int jt = 0; jt < 16; ++jt) {
    const char* kcur = (jt & 1) ? kb1 : kb0;
    const char* vcur = (jt & 1) ? vb1 : vb0;
    if (jt < 15) {
      char* kn = (jt & 1) ? kb0 : kb1;
      char* vn = (jt & 1) ? vb0 : vb1;
      STAGE(kn, vn, jt + 1);
    }

    // ---- S^T = K.Q over the 32-j tile ----
    f32x16 sacc;
    #pragma unroll
    for (int e = 0; e < 16; ++e) sacc[e] = 0.f;
    __builtin_amdgcn_s_setprio(1);
    #pragma unroll
    for (int ks = 0; ks < 16; ++ks) {
      f16x8 kf = *(const f16x8*)(kcur + kxread + ((((ks * 2 + hi) ^ l31) & 31) << 4));
      sacc = __builtin_amdgcn_mfma_f32_32x32x16_f16(kf, qf[ks], sacc, 0, 0, 0);
    }
    __builtin_amdgcn_s_setprio(0);

    // ---- online softmax, in-lane (one query per lane) ----
    float pm;
    {
      float a = fmaxf(fmaxf(sacc[0], sacc[1]), fmaxf(sacc[2], sacc[3]));
      float bmx = fmaxf(fmaxf(sacc[4], sacc[5]), fmaxf(sacc[6], sacc[7]));
      float c2 = fmaxf(fmaxf(sacc[8], sacc[9]), fmaxf(sacc[10], sacc[11]));
      float d = fmaxf(fmaxf(sacc[12], sacc[13]), fmaxf(sacc[14], sacc[15]));
      pm = fmaxf(fmaxf(a, bmx), fmaxf(c2, d));
    }
    pm = fmaxf(pm, __shfl_xor(pm, 32));
    if (__any(pm > m + 8.f)) {          // T13 defer-max
      float mn = fmaxf(m, pm);
      float co = __expf(m - mn);
      lsum *= co;
      #pragma unroll
      for (int ct = 0; ct < 8; ++ct)
        #pragma unroll
        for (int e = 0; e < 16; ++e) oacc[ct][e] *= co;
      m = mn;
    }
    float ls = 0.f;
    #pragma unroll
    for (int e = 0; e < 16; ++e) {
      float pv = __expf(sacc[e] - m);
      sacc[e] = pv;
      ls += pv;
    }
    ls += __shfl_xor(ls, 32);
    lsum += ls;

    // ---- P -> fp16 B-frags via pack + half-swap (no LDS) ----
    unsigned pk0a = pk2(sacc[0], sacc[1]), pk0b = pk2(sacc[2], sacc[3]);
    unsigned pk1a = pk2(sacc[4], sacc[5]), pk1b = pk2(sacc[6], sacc[7]);
    unsigned pk2a = pk2(sacc[8], sacc[9]), pk2b = pk2(sacc[10], sacc[11]);
    unsigned pk3a = pk2(sacc[12], sacc[13]), pk3b = pk2(sacc[14], sacc[15]);
    unsigned tx0 = hi ? pk0a : pk1a, tx1 = hi ? pk0b : pk1b;
    unsigned tx2 = hi ? pk2a : pk3a, tx3 = hi ? pk2b : pk3b;
    unsigned rx0 = (unsigned)__shfl_xor((int)tx0, 32);
    unsigned rx1 = (unsigned)__shfl_xor((int)tx1, 32);
    unsigned rx2 = (unsigned)__shfl_xor((int)tx2, 32);
    unsigned rx3 = (unsigned)__shfl_xor((int)tx3, 32);
    u32x4 w0, w1;
    w0[0] = hi ? rx0 : pk0a;  w0[1] = hi ? rx1 : pk0b;
    w0[2] = hi ? pk1a : rx0;  w0[3] = hi ? pk1b : rx1;
    w1[0] = hi ? rx2 : pk2a;  w1[1] = hi ? rx3 : pk2b;
    w1[2] = hi ? pk3a : rx2;  w1[3] = hi ? pk3b : rx3;
    f16x8 pf0 = __builtin_bit_cast(f16x8, w0);
    f16x8 pf1 = __builtin_bit_cast(f16x8, w1);

    // ---- O^T += V.P^T ----
    __builtin_amdgcn_s_setprio(1);
    #pragma unroll
    for (int ct = 0; ct < 8; ++ct) {
      f16x8 va = *(const f16x8*)(vcur + ct * 2048 + vr0);
      oacc[ct] = __builtin_amdgcn_mfma_f32_32x32x16_f16(va, pf0, oacc[ct], 0, 0, 0);
      f16x8 vb = *(const f16x8*)(vcur + ct * 2048 + vr1);
      oacc[ct] = __builtin_amdgcn_mfma_f32_32x32x16_f16(vb, pf1, oacc[ct], 0, 0, 0);
    }
    __builtin_amdgcn_s_setprio(0);

    __syncthreads();  // drains staging loads; next tile ready, buffers swappable
  }
#undef STAGE

  // ---- store unnormalized partials + m/l planes ----
  const int slot = jq * 4 + b;
  _Float16* pOq = pO + ((size_t)slot << 20);   // [256 c][4096 i]
  #pragma unroll
  for (int ct = 0; ct < 8; ++ct)
    #pragma unroll
    for (int r = 0; r < 16; ++r) {
      int c = ct * 32 + (r & 3) + 8 * (r >> 2) + 4 * hi;
      pOq[((size_t)c << 12) + irow] = (_Float16)oacc[ct][r];
    }
  if (hi == 0) {
    pml[(size_t)slot * 8192 + irow] = m;
    pml[(size_t)slot * 8192 + 4096 + irow] = lsum;
  }
}

// ---------------- kernel 3: combine 8 j-slice partials + residual ----------------
// grid (64 i-chunks, 4 b), 256 thr, fully coalesced f16x8 runs.
__global__ __launch_bounds__(256) void comb_kernel(
    const _Float16* __restrict__ pO, const float* __restrict__ pml,
    const float* __restrict__ x, const float* __restrict__ gamma,
    float* __restrict__ out) {
  const int t = threadIdx.x;
  const int b = blockIdx.y;
  const int ci = t >> 3;                   // 0..31
  const int i8 = blockIdx.x * 64 + (t & 7) * 8;
  const float g = gamma[0];

  // folded weights: wq[q][ii] = g * exp(m_q - M) / den
  float mq[8][8], lq[8][8];
  #pragma unroll
  for (int q = 0; q < 8; ++q) {
    const float* base = pml + (size_t)(q * 4 + b) * 8192 + i8;
    *(f32x4*)&mq[q][0] = *(const f32x4*)base;
    *(f32x4*)&mq[q][4] = *(const f32x4*)(base + 4);
    *(f32x4*)&lq[q][0] = *(const f32x4*)(base + 4096);
    *(f32x4*)&lq[q][4] = *(const f32x4*)(base + 4100);
  }
  float wq[8][8];
  #pragma unroll
  for (int ii = 0; ii < 8; ++ii) {
    float M = -1e30f;
    #pragma unroll
    for (int q = 0; q < 8; ++q) M = fmaxf(M, mq[q][ii]);
    float den = 0.f;
    #pragma unroll
    for (int q = 0; q < 8; ++q) {
      float wv = __expf(mq[q][ii] - M);
      wq[q][ii] = wv;
      den += wv * lq[q][ii];
    }
    float sc = g / den;
    #pragma unroll
    for (int q = 0; q < 8; ++q) wq[q][ii] *= sc;
  }

  #pragma unroll
  for (int cs = 0; cs < 8; ++cs) {
    int c = ci + cs * 32;
    float o8[8] = {0.f, 0.f, 0.f, 0.f, 0.f, 0.f, 0.f, 0.f};
    #pragma unroll
    for (int q = 0; q < 8; ++q) {
      f16x8 p8 = *(const f16x8*)(pO + (((size_t)((q * 4 + b) * 256 + c)) << 12) + i8);
      #pragma unroll
      for (int ii = 0; ii < 8; ++ii) o8[ii] += (float)p8[ii] * wq[q][ii];
    }
    size_t xo = (((size_t)(b * 256 + c)) << 12) + i8;
    f32x4 x0 = *(const f32x4*)(x + xo);
    f32x4 x1 = *(const f32x4*)(x + xo + 4);
    f32x4 r0, r1;
    #pragma unroll
    for (int ii = 0; ii < 4; ++ii) {
      r0[ii] = o8[ii] + x0[ii];
      r1[ii] = o8[ii + 4] + x1[ii];
    }
    *(f32x4*)(out + xo) = r0;
    *(f32x4*)(out + xo + 4) = r1;
  }
}

extern "C" void kernel_launch(void* const* d_in, const int* in_sizes, int n_in,
                              void* d_out, int out_size, void* d_ws, size_t ws_size,
                              hipStream_t stream) {
  const float* x     = (const float*)d_in[0];
  const float* Wq    = (const float*)d_in[1];
  const float* bq    = (const float*)d_in[2];
  const float* Wk    = (const float*)d_in[3];
  const float* bk    = (const float*)d_in[4];
  const float* Wv    = (const float*)d_in[5];
  const float* bv    = (const float*)d_in[6];
  const float* gamma = (const float*)d_in[7];
  float* out = (float*)d_out;

  _Float16* ws16 = (_Float16*)d_ws;
  const size_t SZ = (size_t)B_ * N_ * C_;   // 4,194,304
  _Float16* Qf  = ws16;
  _Float16* Kf  = ws16 + SZ;
  _Float16* Vf  = ws16 + 2 * SZ;
  _Float16* wqf = ws16 + 3 * SZ;
  _Float16* wkf = wqf + 65536;
  _Float16* wvf = wqf + 2 * 65536;
  _Float16* pO  = wqf + 3 * 65536;          // 32 x [256][4096] f16 = 67 MB
  float*    pml = (float*)(pO + (size_t)32 * 256 * 4096);  // 32 x [2][4096] f32

  wconv_kernel<<<dim3(256), 256, 0, stream>>>(Wq, Wk, Wv, wqf, wkf, wvf);
  proj_kernel<<<dim3(64, 4), 256, 0, stream>>>(x, wqf, wkf, wvf, bq, bk, bv, Qf, Kf, Vf);
  attn_kernel<<<dim3(16, 8, 4), 512, 0, stream>>>(Qf, Kf, Vf, pO, pml);
  comb_kernel<<<dim3(64, 4), 256, 0, stream>>>(pO, pml, x, gamma, out);
}

// Round 7
// 206.792 us; speedup vs baseline: 5.5322x; 5.5322x over previous
//
#include <hip/hip_runtime.h>

#define B_ 4
#define C_ 256
#define N_ 4096

typedef float f32x4 __attribute__((ext_vector_type(4)));
typedef float f32x16 __attribute__((ext_vector_type(16)));
typedef _Float16 f16x8 __attribute__((ext_vector_type(8)));
typedef _Float16 f16x4 __attribute__((ext_vector_type(4)));
typedef _Float16 f16x2 __attribute__((ext_vector_type(2)));
typedef unsigned u32x4 __attribute__((ext_vector_type(4)));

__device__ __forceinline__ unsigned pk2(float a, float b) {
  f16x2 t = {(_Float16)a, (_Float16)b};
  return __builtin_bit_cast(unsigned, t);
}
__device__ __forceinline__ void gll16(const void* g, void* l) {
  __builtin_amdgcn_global_load_lds(
      (const __attribute__((address_space(1))) unsigned*)g,
      (__attribute__((address_space(3))) unsigned*)l, 16, 0, 0);
}

// ---------------- kernel 0: W fp32 -> fp16 ----------------
__global__ void wconv_kernel(const float* __restrict__ Wq, const float* __restrict__ Wk,
                             const float* __restrict__ Wv,
                             _Float16* __restrict__ wqf, _Float16* __restrict__ wkf,
                             _Float16* __restrict__ wvf) {
  int i = blockIdx.x * 256 + threadIdx.x;
  wqf[i] = (_Float16)Wq[i];
  wkf[i] = (_Float16)Wk[i];
  wvf[i] = (_Float16)Wv[i];
}

// ---------------- kernel 1: QKV projection, full 256-o per block ----------------
// grid (64 n-tiles, 4 b), 256 thr. LDS-bounce epilogues for coalesced stores.
__global__ __launch_bounds__(256) void proj_kernel(
    const float* __restrict__ x,
    const _Float16* __restrict__ wqf, const _Float16* __restrict__ wkf,
    const _Float16* __restrict__ wvf,
    const float* __restrict__ bq, const float* __restrict__ bk,
    const float* __restrict__ bv,
    _Float16* __restrict__ Qf, _Float16* __restrict__ Kf, _Float16* __restrict__ Vf) {
  __shared__ __align__(16) _Float16 xT[64 * 264];   // [n][c], pitch 264
  __shared__ __align__(16) char oBuf[36864];        // Q/K: [64 n][264 o] f16; V: [256 o][72 n] f16
  const int t = threadIdx.x;
  const int n0 = blockIdx.x * 64, b = blockIdx.y;
  const float* xb = x + (size_t)b * C_ * N_ + n0;

  // stage x tile transposed to f16: 4c x 4n micro-transposes
  #pragma unroll
  for (int it = 0; it < 4; ++it) {
    int c0 = ((t >> 4) + it * 16) * 4;
    int n4 = (t & 15) * 4;
    f32x4 r0 = *(const f32x4*)(xb + (size_t)(c0 + 0) * N_ + n4);
    f32x4 r1 = *(const f32x4*)(xb + (size_t)(c0 + 1) * N_ + n4);
    f32x4 r2 = *(const f32x4*)(xb + (size_t)(c0 + 2) * N_ + n4);
    f32x4 r3 = *(const f32x4*)(xb + (size_t)(c0 + 3) * N_ + n4);
    #pragma unroll
    for (int nn = 0; nn < 4; ++nn) {
      f16x4 v = {(_Float16)r0[nn], (_Float16)r1[nn], (_Float16)r2[nn], (_Float16)r3[nn]};
      *(f16x4*)(xT + (n4 + nn) * 264 + c0) = v;
    }
  }
  __syncthreads();

  const int wv = t >> 6, lane = t & 63, l15 = lane & 15, lg = lane >> 4;
  _Float16* oB = (_Float16*)oBuf;

  // ---- Q and K paths: D[n][o], wave owns 16 n-rows, loops all 16 o-tiles ----
  #pragma unroll
  for (int path = 0; path < 2; ++path) {
    const _Float16* wp = path ? wkf : wqf;
    const float* bp = path ? bk : bq;
    _Float16* op = path ? Kf : Qf;
    f32x4 acc[16];
    #pragma unroll
    for (int os = 0; os < 16; ++os)
      #pragma unroll
      for (int e = 0; e < 4; ++e) acc[os][e] = 0.f;
    #pragma unroll
    for (int cs = 0; cs < 8; ++cs) {
      int c0 = cs * 32 + lg * 8;
      f16x8 a = *(const f16x8*)(xT + (wv * 16 + l15) * 264 + c0);
      #pragma unroll
      for (int os = 0; os < 16; ++os) {
        f16x8 bb = *(const f16x8*)(wp + (size_t)(os * 16 + l15) * 256 + c0);
        acc[os] = __builtin_amdgcn_mfma_f32_16x16x32_f16(a, bb, acc[os], 0, 0, 0);
      }
    }
    if (path == 1) __syncthreads();   // Q coop-store reads of oB done
    #pragma unroll
    for (int os = 0; os < 16; ++os) {
      int o = os * 16 + l15;
      float bbv = bp[o];
      #pragma unroll
      for (int r = 0; r < 4; ++r)
        oB[(wv * 16 + lg * 4 + r) * 264 + o] = (_Float16)(acc[os][r] + bbv);
    }
    __syncthreads();
    {
      int row = t >> 2, q4 = t & 3;
      const char* src = (const char*)oB + row * 528 + q4 * 16;
      char* dst = (char*)op + ((size_t)(b * N_ + n0 + row)) * 512 + q4 * 16;
      #pragma unroll
      for (int u = 0; u < 8; ++u)
        *(f16x8*)(dst + u * 64) = *(const f16x8*)(src + u * 64);
    }
  }

  // ---- V path: D[o][n], wave owns 64 o-rows x all 4 n-tiles ----
  {
    f32x4 acc[4][4];
    #pragma unroll
    for (int oi = 0; oi < 4; ++oi)
      #pragma unroll
      for (int nt = 0; nt < 4; ++nt)
        #pragma unroll
        for (int e = 0; e < 4; ++e) acc[oi][nt][e] = 0.f;
    #pragma unroll
    for (int cs = 0; cs < 8; ++cs) {
      int c0 = cs * 32 + lg * 8;
      f16x8 a[4];
      #pragma unroll
      for (int oi = 0; oi < 4; ++oi)
        a[oi] = *(const f16x8*)(wvf + (size_t)(wv * 64 + oi * 16 + l15) * 256 + c0);
      #pragma unroll
      for (int nt = 0; nt < 4; ++nt) {
        f16x8 bb = *(const f16x8*)(xT + (nt * 16 + l15) * 264 + c0);
        #pragma unroll
        for (int oi = 0; oi < 4; ++oi)
          acc[oi][nt] = __builtin_amdgcn_mfma_f32_16x16x32_f16(a[oi], bb, acc[oi][nt], 0, 0, 0);
      }
    }
    __syncthreads();   // K coop-store reads of oB done
    #pragma unroll
    for (int oi = 0; oi < 4; ++oi)
      #pragma unroll
      for (int r = 0; r < 4; ++r) {
        int o = wv * 64 + oi * 16 + lg * 4 + r;
        float bbv = bv[o];
        #pragma unroll
        for (int nt = 0; nt < 4; ++nt)
          oB[o * 72 + nt * 16 + l15] = (_Float16)(acc[oi][nt][r] + bbv);
      }
    __syncthreads();
    {
      const char* src = oBuf + t * 144;
      char* dst = (char*)Vf + ((size_t)(b * C_ + t)) * 8192 + n0 * 2;
      #pragma unroll
      for (int u = 0; u < 8; ++u)
        *(f16x8*)(dst + u * 16) = *(const f16x8*)(src + u * 16);
    }
  }
}

// ---------------- kernel 2: flash attention partials ----------------
// grid (16 i-macro, 4 jq, 4 b), 512 thr = 8 waves, wave owns 32 i-rows; block
// walks 32 tiles of 32 j over its 1024-j quarter. 3-deep rotating LDS staging
// with counted s_waitcnt vmcnt(4) + raw s_barrier (T4: never drain to 0 in
// steady state; staged loads get 2 tile-times of latency cover). setprio on
// MFMA clusters. Outputs unnormalized O (f16) + m/l planes (f32).
__global__ __launch_bounds__(512, 2) void attn_kernel(
    const _Float16* __restrict__ Qf, const _Float16* __restrict__ Kf,
    const _Float16* __restrict__ Vf,
    _Float16* __restrict__ pO, float* __restrict__ pml) {
  __shared__ __align__(16) char smem[98304];  // 3 x (K 16KB + V 16KB)

  const int t = threadIdx.x;
  const int w = t >> 6, lane = t & 63;
  const int l31 = lane & 31, hi = lane >> 5;
  const int i0 = blockIdx.x * 256, jq = blockIdx.y, b = blockIdx.z;

  // ---- Q prologue: lane column = own query row ----
  const int irow = i0 + w * 32 + l31;
  const _Float16* qb = Qf + ((size_t)(b * N_ + irow)) * C_;
  f16x8 qf[16];
  #pragma unroll
  for (int ks = 0; ks < 16; ++ks) qf[ks] = *(const f16x8*)(qb + ks * 16 + hi * 8);

  f32x16 oacc[8];
  #pragma unroll
  for (int ct = 0; ct < 8; ++ct)
    #pragma unroll
    for (int e = 0; e < 16; ++e) oacc[ct][e] = 0.f;
  float m = -1e30f, lsum = 0.f;

  const char* Kg = (const char*)(Kf + (size_t)b * N_ * C_);
  const char* Vg = (const char*)(Vf + (size_t)b * C_ * N_);
  const int jb0 = jq * 1024;

  const int kxread = l31 << 9;
  const int vq = (l31 >> 3) & 3;
  const int vr0 = l31 * 64 + ((hi ^ vq) << 4);
  const int vr1 = l31 * 64 + (((2 | hi) ^ vq) << 4);

  // K LDS [32 j][32 slots of 16B], slot s holds global c-slot (s^j)&31.
  // V LDS [256 c][4 slots of 16B], slot s holds global j-slot s^((c>>3)&3).
  // Each STAGE = 4 global_load_lds insts per wave (vmcnt +=4).
#define STAGE(buf_, jtn) do {                                                    \
    int jb_ = jb0 + (jtn) * 32;                                                  \
    char* kd_ = (buf_);                                                          \
    char* vd_ = (buf_) + 16384;                                                  \
    const char* kg_ = Kg + ((size_t)jb_ << 9);                                   \
    _Pragma("unroll")                                                            \
    for (int u = 0; u < 2; ++u) {                                                \
      int jl_ = w * 4 + u * 2 + (lane >> 5);                                     \
      gll16(kg_ + (jl_ << 9) + ((((lane & 31) ^ jl_) & 31) << 4),                \
            kd_ + (w * 4 + u * 2) * 512);                                        \
    }                                                                            \
    const char* vg_ = Vg + ((size_t)jb_ << 1);                                   \
    _Pragma("unroll")                                                            \
    for (int u = 0; u < 2; ++u) {                                                \
      int c_ = w * 32 + u * 16 + (lane >> 2);                                    \
      gll16(vg_ + ((size_t)c_ << 13) + (((lane & 3) ^ ((c_ >> 3) & 3)) << 4),    \
            vd_ + (w * 32 + u * 16) * 64);                                       \
    }                                                                            \
  } while (0)

  STAGE(smem, 0);
  STAGE(smem + 32768, 1);

  int coff = 0, noff = 32768, soff = 65536;   // rotating 3-buffer offsets

  for (int jt = 0; jt < 32; ++jt) {
    // tile jt ready when all but the newest 4 (tile jt+1's) loads are done
    if (jt < 31) asm volatile("s_waitcnt vmcnt(4)" ::: "memory");
    else         asm volatile("s_waitcnt vmcnt(0)" ::: "memory");
    __builtin_amdgcn_s_barrier();
    __builtin_amdgcn_sched_barrier(0);

    if (jt < 30) STAGE(smem + soff, jt + 2);   // overwrites tile jt-1's buffer

    const char* kcur = smem + coff;
    const char* vcur = kcur + 16384;

    // ---- S^T = K.Q over the 32-j tile ----
    f32x16 sacc;
    #pragma unroll
    for (int e = 0; e < 16; ++e) sacc[e] = 0.f;
    __builtin_amdgcn_s_setprio(1);
    #pragma unroll
    for (int ks = 0; ks < 16; ++ks) {
      f16x8 kf = *(const f16x8*)(kcur + kxread + ((((ks * 2 + hi) ^ l31) & 31) << 4));
      sacc = __builtin_amdgcn_mfma_f32_32x32x16_f16(kf, qf[ks], sacc, 0, 0, 0);
    }
    __builtin_amdgcn_s_setprio(0);

    // ---- online softmax, in-lane (one query per lane) ----
    float pm;
    {
      float a = fmaxf(fmaxf(sacc[0], sacc[1]), fmaxf(sacc[2], sacc[3]));
      float bmx = fmaxf(fmaxf(sacc[4], sacc[5]), fmaxf(sacc[6], sacc[7]));
      float c2 = fmaxf(fmaxf(sacc[8], sacc[9]), fmaxf(sacc[10], sacc[11]));
      float d = fmaxf(fmaxf(sacc[12], sacc[13]), fmaxf(sacc[14], sacc[15]));
      pm = fmaxf(fmaxf(a, bmx), fmaxf(c2, d));
    }
    pm = fmaxf(pm, __shfl_xor(pm, 32));
    if (__any(pm > m + 8.f)) {          // T13 defer-max
      float mn = fmaxf(m, pm);
      float co = __expf(m - mn);
      lsum *= co;
      #pragma unroll
      for (int ct = 0; ct < 8; ++ct)
        #pragma unroll
        for (int e = 0; e < 16; ++e) oacc[ct][e] *= co;
      m = mn;
    }
    float ls = 0.f;
    #pragma unroll
    for (int e = 0; e < 16; ++e) {
      float pv = __expf(sacc[e] - m);
      sacc[e] = pv;
      ls += pv;
    }
    ls += __shfl_xor(ls, 32);
    lsum += ls;

    // ---- P -> fp16 B-frags via pack + half-swap (no LDS) ----
    unsigned pk0a = pk2(sacc[0], sacc[1]), pk0b = pk2(sacc[2], sacc[3]);
    unsigned pk1a = pk2(sacc[4], sacc[5]), pk1b = pk2(sacc[6], sacc[7]);
    unsigned pk2a = pk2(sacc[8], sacc[9]), pk2b = pk2(sacc[10], sacc[11]);
    unsigned pk3a = pk2(sacc[12], sacc[13]), pk3b = pk2(sacc[14], sacc[15]);
    unsigned tx0 = hi ? pk0a : pk1a, tx1 = hi ? pk0b : pk1b;
    unsigned tx2 = hi ? pk2a : pk3a, tx3 = hi ? pk2b : pk3b;
    unsigned rx0 = (unsigned)__shfl_xor((int)tx0, 32);
    unsigned rx1 = (unsigned)__shfl_xor((int)tx1, 32);
    unsigned rx2 = (unsigned)__shfl_xor((int)tx2, 32);
    unsigned rx3 = (unsigned)__shfl_xor((int)tx3, 32);
    u32x4 w0, w1;
    w0[0] = hi ? rx0 : pk0a;  w0[1] = hi ? rx1 : pk0b;
    w0[2] = hi ? pk1a : rx0;  w0[3] = hi ? pk1b : rx1;
    w1[0] = hi ? rx2 : pk2a;  w1[1] = hi ? rx3 : pk2b;
    w1[2] = hi ? pk3a : rx2;  w1[3] = hi ? pk3b : rx3;
    f16x8 pf0 = __builtin_bit_cast(f16x8, w0);
    f16x8 pf1 = __builtin_bit_cast(f16x8, w1);

    // ---- O^T += V.P^T ----
    __builtin_amdgcn_s_setprio(1);
    #pragma unroll
    for (int ct = 0; ct < 8; ++ct) {
      f16x8 va = *(const f16x8*)(vcur + ct * 2048 + vr0);
      oacc[ct] = __builtin_amdgcn_mfma_f32_32x32x16_f16(va, pf0, oacc[ct], 0, 0, 0);
      f16x8 vb = *(const f16x8*)(vcur + ct * 2048 + vr1);
      oacc[ct] = __builtin_amdgcn_mfma_f32_32x32x16_f16(vb, pf1, oacc[ct], 0, 0, 0);
    }
    __builtin_amdgcn_s_setprio(0);

    int tmp = coff; coff = noff; noff = soff; soff = tmp;   // rotate buffers
  }
#undef STAGE

  // ---- store unnormalized partials + m/l planes ----
  const int slot = jq * 4 + b;
  _Float16* pOq = pO + ((size_t)slot << 20);   // [256 c][4096 i]
  #pragma unroll
  for (int ct = 0; ct < 8; ++ct)
    #pragma unroll
    for (int r = 0; r < 16; ++r) {
      int c = ct * 32 + (r & 3) + 8 * (r >> 2) + 4 * hi;
      pOq[((size_t)c << 12) + irow] = (_Float16)oacc[ct][r];
    }
  if (hi == 0) {
    pml[(size_t)slot * 8192 + irow] = m;
    pml[(size_t)slot * 8192 + 4096 + irow] = lsum;
  }
}

// ---------------- kernel 3: combine 4 j-quarter partials + residual ----------------
// grid (64 i-chunks, 4 b), 256 thr, fully coalesced f16x8 runs.
__global__ __launch_bounds__(256) void comb_kernel(
    const _Float16* __restrict__ pO, const float* __restrict__ pml,
    const float* __restrict__ x, const float* __restrict__ gamma,
    float* __restrict__ out) {
  const int t = threadIdx.x;
  const int b = blockIdx.y;
  const int ci = t >> 3;                   // 0..31
  const int i8 = blockIdx.x * 64 + (t & 7) * 8;
  const float g = gamma[0];

  // folded weights: wq[q][ii] = g * exp(m_q - M) / den
  float mq[4][8], lq[4][8];
  #pragma unroll
  for (int q = 0; q < 4; ++q) {
    const float* base = pml + (size_t)(q * 4 + b) * 8192 + i8;
    *(f32x4*)&mq[q][0] = *(const f32x4*)base;
    *(f32x4*)&mq[q][4] = *(const f32x4*)(base + 4);
    *(f32x4*)&lq[q][0] = *(const f32x4*)(base + 4096);
    *(f32x4*)&lq[q][4] = *(const f32x4*)(base + 4100);
  }
  float wq[4][8];
  #pragma unroll
  for (int ii = 0; ii < 8; ++ii) {
    float M = -1e30f;
    #pragma unroll
    for (int q = 0; q < 4; ++q) M = fmaxf(M, mq[q][ii]);
    float den = 0.f;
    #pragma unroll
    for (int q = 0; q < 4; ++q) {
      float wv = __expf(mq[q][ii] - M);
      wq[q][ii] = wv;
      den += wv * lq[q][ii];
    }
    float sc = g / den;
    #pragma unroll
    for (int q = 0; q < 4; ++q) wq[q][ii] *= sc;
  }

  #pragma unroll
  for (int cs = 0; cs < 8; ++cs) {
    int c = ci + cs * 32;
    float o8[8] = {0.f, 0.f, 0.f, 0.f, 0.f, 0.f, 0.f, 0.f};
    #pragma unroll
    for (int q = 0; q < 4; ++q) {
      f16x8 p8 = *(const f16x8*)(pO + (((size_t)((q * 4 + b) * 256 + c)) << 12) + i8);
      #pragma unroll
      for (int ii = 0; ii < 8; ++ii) o8[ii] += (float)p8[ii] * wq[q][ii];
    }
    size_t xo = (((size_t)(b * 256 + c)) << 12) + i8;
    f32x4 x0 = *(const f32x4*)(x + xo);
    f32x4 x1 = *(const f32x4*)(x + xo + 4);
    f32x4 r0, r1;
    #pragma unroll
    for (int ii = 0; ii < 4; ++ii) {
      r0[ii] = o8[ii] + x0[ii];
      r1[ii] = o8[ii + 4] + x1[ii];
    }
    *(f32x4*)(out + xo) = r0;
    *(f32x4*)(out + xo + 4) = r1;
  }
}

extern "C" void kernel_launch(void* const* d_in, const int* in_sizes, int n_in,
                              void* d_out, int out_size, void* d_ws, size_t ws_size,
                              hipStream_t stream) {
  const float* x     = (const float*)d_in[0];
  const float* Wq    = (const float*)d_in[1];
  const float* bq    = (const float*)d_in[2];
  const float* Wk    = (const float*)d_in[3];
  const float* bk    = (const float*)d_in[4];
  const float* Wv    = (const float*)d_in[5];
  const float* bv    = (const float*)d_in[6];
  const float* gamma = (const float*)d_in[7];
  float* out = (float*)d_out;

  _Float16* ws16 = (_Float16*)d_ws;
  const size_t SZ = (size_t)B_ * N_ * C_;   // 4,194,304
  _Float16* Qf  = ws16;
  _Float16* Kf  = ws16 + SZ;
  _Float16* Vf  = ws16 + 2 * SZ;
  _Float16* wqf = ws16 + 3 * SZ;
  _Float16* wkf = wqf + 65536;
  _Float16* wvf = wqf + 2 * 65536;
  _Float16* pO  = wqf + 3 * 65536;          // 16 x [256][4096] f16 = 32 MB
  float*    pml = (float*)(pO + (size_t)16 * 256 * 4096);  // 16 x [2][4096] f32

  wconv_kernel<<<dim3(256), 256, 0, stream>>>(Wq, Wk, Wv, wqf, wkf, wvf);
  proj_kernel<<<dim3(64, 4), 256, 0, stream>>>(x, wqf, wkf, wvf, bq, bk, bv, Qf, Kf, Vf);
  attn_kernel<<<dim3(16, 4, 4), 512, 0, stream>>>(Qf, Kf, Vf, pO, pml);
  comb_kernel<<<dim3(64, 4), 256, 0, stream>>>(pO, pml, x, gamma, out);
}